// Round 9
// baseline (414.426 us; speedup 1.0000x reference)
//
#include <hip/hip_runtime.h>
#include <hip/hip_bf16.h>

#define N_ROWS   131072
#define M_PROTO  512
#define OUT_R1   8388608
#define OUT_R2   8388609
#define OUT_R3   8388610
#define OUT_LAT  8388611
#define BIGVAL   1000000.0f
#define INF_BITS 0x7F800000

typedef __attribute__((ext_vector_type(8)))  short bf16x8;   // 8 bf16 (4 VGPRs)
typedef __attribute__((ext_vector_type(16))) float f32x16;   // 32x32 C/D frag

// lgkm-only barrier: orders LDS writes across waves WITHOUT draining vmcnt —
// global stores stay in flight across iterations (T4). Asm "memory" clobbers
// pin LDS ops at compile time on both sides; sched_barrier stops scheduler
// motion (rule #18); s_barrier gives the runtime rendezvous.
#define BAR_LGKM() do {                                        \
    asm volatile("s_waitcnt lgkmcnt(0)" ::: "memory");         \
    __builtin_amdgcn_s_barrier();                              \
    asm volatile("" ::: "memory");                             \
    __builtin_amdgcn_sched_barrier(0);                         \
} while (0)

static __device__ __forceinline__ unsigned int f2bf(float f) {
    __hip_bfloat16 h = __float2bfloat16(f);     // RNE convert
    return (unsigned int)__builtin_bit_cast(unsigned short, h);
}

// ---------------- init: colmin = +inf bits, accumulators = 0 ----------------
__global__ __launch_bounds__(512) void init_kernel(int* __restrict__ colmin,
                                                   float* __restrict__ acc) {
    colmin[threadIdx.x] = INF_BITS;
    if (threadIdx.x == 0) { acc[0] = 0.f; acc[1] = 0.f; }
}

// --- proto: PP[j] = ||p_j||^2, R3 row-mins (verified), + bf16 B pre-swizzle --
__global__ __launch_bounds__(256) void proto_kernel(const float* __restrict__ p,
                                                    float* __restrict__ PP,
                                                    float* __restrict__ acc,
                                                    unsigned char* __restrict__ Bbf) {
    const int j  = blockIdx.x;
    const int ln = threadIdx.x & 63;
    const int wv = threadIdx.x >> 6;
    const float* prow = p + j * 64;
    const float pjl = prow[ln];
    float pp = 0.f;
    #pragma unroll
    for (int k = 0; k < 64; ++k) { const float t = prow[k]; pp = fmaf(t, t, pp); }
    float rmin = INFINITY;
    for (int jp = wv; jp < M_PROTO; jp += 4) {
        float t = pjl * p[jp * 64 + ln];
        #pragma unroll
        for (int sh = 1; sh < 64; sh <<= 1) t += __shfl_xor(t, sh, 64);
        float d = fmaf(-2.f, t, pp + pp);
        if (d == 0.0f) d = BIGVAL;
        rmin = fminf(rmin, d);
    }
    __shared__ float sm[4];
    if (ln == 0) sm[wv] = rmin;
    __syncthreads();
    if (threadIdx.x == 0) {
        const float m = fminf(fminf(sm[0], sm[1]), fminf(sm[2], sm[3]));
        atomicAdd(&acc[1], m);
        PP[j] = pp;
    }
    if (threadIdx.x < 16) {
        const int seg = threadIdx.x;
        const float4 v = ((const float4*)p)[j * 16 + seg];
        const unsigned int lo = f2bf(v.x) | (f2bf(v.y) << 16);
        const unsigned int hi = f2bf(v.z) | (f2bf(v.w) << 16);
        const int byte = (j * 128 + seg * 8) ^ ((j & 7) << 4);
        *(uint2*)(Bbf + byte) = make_uint2(lo, hi);
    }
}

// ------------- main: 256 rows/block, 4-iter, lgkm-only in-loop barriers -----
// Identical to round 8 except: (1) in-loop __syncthreads() -> BAR_LGKM(), so
// lat/outx stores never block a barrier and drain in the background; (2) col-
// min kept in registers across iters (same 4 cols/thread every iter), one LDS
// atomic phase after the loop.
__global__ __launch_bounds__(512, 4) void main_kernel(const float* __restrict__ x,
                                                      const uint4* __restrict__ Bbf,
                                                      const float* __restrict__ PP,
                                                      float* __restrict__ outx,
                                                      float* __restrict__ lat,
                                                      int* __restrict__ colmin_g,
                                                      float* __restrict__ acc_g) {
    __shared__ __align__(16) unsigned char Bl[512 * 128];   // 64 KB pre-swizzled image
    __shared__ __align__(16) unsigned char Al[64 * 128];    // 8 KB
    __shared__ float xx_lds[64];
    __shared__ float pp_lds[512];
    __shared__ int   cmin_lds[512];
    __shared__ int   rowmin_lds[64];
    __shared__ float rsum_lds[1];

    const int tid = threadIdx.x;
    const int l   = tid & 63;
    const int w   = tid >> 6;
    const int rg  = w >> 2;        // 0..1 : 32-row group
    const int cg  = w & 3;         // 0..3 : 128-col group
    const int h   = l >> 5;        // half-wave
    const int lc  = l & 31;

    // ---- one-time block setup ----
    cmin_lds[tid] = INF_BITS;
    pp_lds[tid]   = PP[tid];
    if (tid < 64) rowmin_lds[tid] = INF_BITS;
    if (tid == 0) rsum_lds[0] = 0.f;
    #pragma unroll
    for (int it = 0; it < 8; ++it) {           // stage B: plain 16B copies
        const int idx = it * 512 + tid;
        *(uint4*)(Bl + idx * 16) = Bbf[idx];
    }

    const size_t x4base = (size_t)blockIdx.x * 4096;   // 256 rows * 16 float4
    const float4* x4 = (const float4*)x;
    float4*       o4 = (float4*)outx;
    float4 xf0 = x4[x4base + tid];                      // iter-0 x in regs
    float4 xf1 = x4[x4base + 512 + tid];

    __syncthreads();               // setup ordering (pp_lds etc.) — full, once

    const int arow  = rg * 32 + lc;
    const int aswz  = (arow & 7) << 4;
    const int abase = arow * 128 + h * 16;
    float ppc[4];
    #pragma unroll
    for (int t = 0; t < 4; ++t) ppc[t] = pp_lds[cg * 128 + t * 32 + lc];

    float cmv[4] = {INFINITY, INFINITY, INFINITY, INFINITY};   // cols fixed/iter

    for (int it = 0; it < 4; ++it) {
        // ---- stage x: Al (swizzled bf16) + outx copy + XX ----
        #pragma unroll
        for (int rep = 0; rep < 2; ++rep) {
            const float4 v   = rep ? xf1 : xf0;
            const int    idx = rep * 512 + tid;
            const int    row = idx >> 4, seg = idx & 15;
            o4[x4base + it * 1024 + idx] = v;
            float sq = v.x * v.x + v.y * v.y + v.z * v.z + v.w * v.w;
            const unsigned int lo = f2bf(v.x) | (f2bf(v.y) << 16);
            const unsigned int hi = f2bf(v.z) | (f2bf(v.w) << 16);
            const int byte = (row * 128 + seg * 8) ^ ((row & 7) << 4);
            *(uint2*)(Al + byte) = make_uint2(lo, hi);
            #pragma unroll
            for (int sh = 1; sh < 16; sh <<= 1) sq += __shfl_xor(sq, sh, 64);
            if ((l & 15) == 0) xx_lds[row] = sq;
        }
        BAR_LGKM();                            // barrier A — no vmcnt drain

        // ---- prefetch next iter's x (drains in background) ----
        if (it < 3) {
            xf0 = x4[x4base + (it + 1) * 1024 + tid];
            xf1 = x4[x4base + (it + 1) * 1024 + 512 + tid];
        }

        // ---- MFMA: wave 32 rows x 128 cols = 4 tiles of 32x32, K=64 ----
        f32x16 acc[4];
        #pragma unroll
        for (int t = 0; t < 4; ++t)
            #pragma unroll
            for (int i = 0; i < 16; ++i) acc[t][i] = 0.f;
        #pragma unroll
        for (int s = 0; s < 4; ++s) {
            const bf16x8 a = *(const bf16x8*)(Al + ((abase + s * 32) ^ aswz));
            #pragma unroll
            for (int t = 0; t < 4; ++t) {
                const int col = cg * 128 + t * 32 + lc;
                const bf16x8 b = *(const bf16x8*)(Bl + ((col * 128 + h * 16 + s * 32) ^ ((col & 7) << 4)));
                acc[t] = __builtin_amdgcn_mfma_f32_32x32x16_bf16(a, b, acc[t], 0, 0, 0);
            }
        }

        // ---- epilogue: dval, 128B-line stores, row mins (col mins in regs) --
        const int rbase = rg * 32 + 4 * h;
        const size_t latrow0 = (size_t)blockIdx.x * 256 + it * 64;
        #pragma unroll
        for (int i = 0; i < 16; ++i) {
            const int rl = rbase + (i & 3) + 8 * (i >> 2);
            const float xxv = xx_lds[rl];
            float rv = INFINITY;
            float* lrow = lat + (latrow0 + rl) * 512 + cg * 128 + lc;
            #pragma unroll
            for (int t = 0; t < 4; ++t) {
                const float dv = xxv + ppc[t] - 2.f * acc[t][i];
                lrow[t * 32] = dv;
                rv = fminf(rv, dv);
                cmv[t] = fminf(cmv[t], dv);
            }
            rv = fminf(rv, __shfl_xor(rv, 8, 64));
            rv = fminf(rv, __shfl_xor(rv, 16, 64));
            if (lc < 8) atomicMin(&rowmin_lds[rl], __float_as_int(rv));
        }
        BAR_LGKM();                            // barrier B — no vmcnt drain

        // ---- per-iter row-min sum (wave 0); reset slots before next iter ----
        if (tid < 64) {
            float r = __int_as_float(rowmin_lds[tid]);
            rowmin_lds[tid] = INF_BITS;        // reset precedes barrier A(it+1)
            #pragma unroll
            for (int sh = 1; sh < 64; sh <<= 1) r += __shfl_xor(r, sh, 64);
            if (tid == 0) rsum_lds[0] += r;
        }
    }
    // ---- col-min combine (regs -> LDS -> global) ----
    #pragma unroll
    for (int t = 0; t < 4; ++t) {
        const float c = fminf(cmv[t], __shfl_xor(cmv[t], 32, 64));
        if (h == 0) atomicMin(&cmin_lds[cg * 128 + t * 32 + lc], __float_as_int(c));
    }
    __syncthreads();                           // final: full drain, once
    atomicMin(&colmin_g[tid], cmin_lds[tid]);
    if (tid == 0) atomicAdd(&acc_g[0], rsum_lds[0]);
}

// ---------------- finalize: scalars --------------------------------------
__global__ __launch_bounds__(512) void finalize_kernel(const int* __restrict__ colmin,
                                                       const float* __restrict__ acc,
                                                       float* __restrict__ out) {
    const int t  = threadIdx.x;
    const int ln = t & 63, wv = t >> 6;
    float s = __int_as_float(colmin[t]);
    #pragma unroll
    for (int sh = 1; sh < 64; sh <<= 1) s += __shfl_xor(s, sh, 64);
    __shared__ float sm[8];
    if (ln == 0) sm[wv] = s;
    __syncthreads();
    if (t == 0) {
        float tot = 0.f;
        #pragma unroll
        for (int q = 0; q < 8; ++q) tot += sm[q];
        out[OUT_R1] = tot / 512.f;
        out[OUT_R2] = acc[0] / 131072.f;
        out[OUT_R3] = acc[1] / 512.f;
    }
}

extern "C" void kernel_launch(void* const* d_in, const int* in_sizes, int n_in,
                              void* d_out, int out_size, void* d_ws, size_t ws_size,
                              hipStream_t stream) {
    const float* x = (const float*)d_in[0];
    const float* p = (const float*)d_in[1];
    float* out = (float*)d_out;
    int*   colmin = (int*)d_ws;                       // [512] ints
    float* acc    = (float*)d_ws + 512;               // [2]
    float* PP     = (float*)d_ws + 1024;              // [512]
    unsigned char* Bbf = (unsigned char*)((float*)d_ws + 4096);  // 64KB, 16B aligned
    float* lat    = out + OUT_LAT;

    hipLaunchKernelGGL(init_kernel,     dim3(1),   dim3(512), 0, stream, colmin, acc);
    hipLaunchKernelGGL(proto_kernel,    dim3(512), dim3(256), 0, stream, p, PP, acc, Bbf);
    hipLaunchKernelGGL(main_kernel,     dim3(512), dim3(512), 0, stream,
                       x, (const uint4*)Bbf, PP, out, lat, colmin, acc);
    hipLaunchKernelGGL(finalize_kernel, dim3(1),   dim3(512), 0, stream, colmin, acc, out);
}